// Round 4
// baseline (1665.259 us; speedup 1.0000x reference)
//
#include <hip/hip_runtime.h>
#include <hip/hip_bf16.h>
#include <stdint.h>

// ContinuousActorCritic: B=256, T=2048, I=128, H=256, A=8
#define BB 256
#define TT 2048
#define II 128
#define HH 256
#define XPLD 260   // s_xp row stride (floats); 256+4 pad keeps write conflicts at free 2-way
#define LOFF 288   // lo half offset in s_h (f16 elems). Byte dist 576 = 64 mod 128
                   // -> lo reads hit banks +16 vs hi: the 8 distinct addrs/instr
                   // tile all 32 banks exactly once (R3 used +256 = 0 mod 128:
                   // 2-way aliasing, 1.34e8 conflict cy = 256 cy/step/CU).

typedef _Float16       f16x8     __attribute__((ext_vector_type(8)));  // 4 VGPR
typedef float          f32x4     __attribute__((ext_vector_type(4)));
typedef unsigned short ushort8_t __attribute__((ext_vector_type(8)));
typedef float          float4_t  __attribute__((ext_vector_type(4)));

__device__ __forceinline__ float bf2f(unsigned short u) {
    union { unsigned int i; float f; } v; v.i = ((unsigned int)u) << 16; return v.f;
}

// R4 = R3 (hi/lo precision split carried in MFMA A-rows: rows %4==0 = h_hi,
// rows %4==1 = h_lo*2048; one ds_read + one MFMA per K-chunk covers both,
// acc reg0 = hi, reg1 = lo, bit-identical to separate chains)
//  + conflict-free lo placement (LOFF=288, see above)
//  + xp-chunk MFMA burst split across slices 8/9 (was 8 MFMA + 8 stores in one
//    step every 16 -> all-wave barrier stall; now 4+4).
// 512 threads = 8 waves = 2/SIMD; wave w owns outputs [w*32, w*32+32) as 2
// N-tiles. xproj batched per 16-step chunk via MFMA M-dim = timesteps.
__global__ __launch_bounds__(512, 2)
void rnn_mfma_r4(const void* __restrict__ xv,  const void* __restrict__ hxv,
                 const void* __restrict__ Wihv, const void* __restrict__ Whhv,
                 const void* __restrict__ Wactv, const void* __restrict__ Wcritv,
                 void* __restrict__ outv)
{
    const int b    = blockIdx.x;
    const int tid  = threadIdx.x;
    const int w    = tid >> 6;            // 0..7
    const int l    = tid & 63;
    const int quad = l >> 4;
    const int col  = l & 15;
    const int tsel = (l >> 4) & 1;        // which N-tile this lane extracts
    const int jown = w * 32 + (l & 31);   // owned output (lanes 32-63 duplicate)
    const int aoff = ((l & 3) == 1) ? LOFF : 0;  // A-row%4==1 lanes feed the lo half

    __shared__ __align__(16) _Float16 s_h[2][2 * LOFF];  // [k]=h_hi, [LOFF+k]=h_lo*2048; dbuf
    __shared__ __align__(16) float    s_xp[2][16 * XPLD];// xproj chunk, dbuf
    __shared__ float s_hf[HH];                           // final h fp32 (heads)
    __shared__ int s_flag;

    // ---- storage-dtype detector (bf16 expected) ----
    if (tid == 0) {
        const unsigned short* p = (const unsigned short*)Whhv;
        int cnt = 0;
        for (int i = 0; i < 256; ++i) { int e = (p[i] >> 7) & 0xFF; cnt += (e > 128) ? 1 : 0; }
        s_flag = (cnt > 16) ? 1 : 0;   // 1 => fp32 storage
    }
    __syncthreads();
    const bool f32io = (s_flag != 0);

    // ---- B-fragments, register-stationary, f16 (bf16->f16 exact) ----
    // bfrag[c*2+t]: lane holds W(j, k0..k0+7), j = w*32 + t*16 + col,
    // k0 = 32c + quad*8.  c 0..7: W_hh; c 8..11: W_ih (xproj chunks).
    f16x8 bfrag[24];
#pragma unroll
    for (int c = 0; c < 12; ++c) {
#pragma unroll
        for (int t = 0; t < 2; ++t) {
            const int j  = w * 32 + t * 16 + col;
            const int k0 = 32 * c + quad * 8;
            f16x8 bv;
            if (!f32io) {
                const unsigned short* src = (k0 < HH)
                    ? ((const unsigned short*)Whhv + j * HH + k0)
                    : ((const unsigned short*)Wihv + j * II + (k0 - HH));
                ushort8_t u = *(const ushort8_t*)src;
#pragma unroll
                for (int e = 0; e < 8; ++e) bv[e] = (_Float16)bf2f(u[e]);
            } else {
                const float* src = (k0 < HH)
                    ? ((const float*)Whhv + j * HH + k0)
                    : ((const float*)Wihv + j * II + (k0 - HH));
#pragma unroll
                for (int e = 0; e < 8; ++e) bv[e] = (_Float16)src[e];
            }
            bfrag[c * 2 + t] = bv;
        }
    }

    const f32x4 kz = {0.f, 0.f, 0.f, 0.f};

    // ---- xproj chunk-prep machinery ----
    // A-frag layout: row m = lane&15 (= timestep-in-chunk), k = (lane>>4)*8+e.
    ushort8_t xru[4];   // raw bf16 prefetch
    float4_t  xrf[8];   // raw fp32 prefetch
    f16x8     xaf[4];   // converted A-frags

    auto xload = [&](int tbase) {
        if (!f32io) {
            const unsigned short* gp = (const unsigned short*)xv
                + ((size_t)b * TT + tbase + col) * II + quad * 8;
#pragma unroll
            for (int c = 0; c < 4; ++c) xru[c] = *(const ushort8_t*)(gp + 32 * c);
        } else {
            const float* gp = (const float*)xv
                + ((size_t)b * TT + tbase + col) * II + quad * 8;
#pragma unroll
            for (int c = 0; c < 4; ++c) {
                xrf[2 * c]     = *(const float4_t*)(gp + 32 * c);
                xrf[2 * c + 1] = *(const float4_t*)(gp + 32 * c + 4);
            }
        }
    };
    auto xcvt = [&]() {
        if (!f32io) {
#pragma unroll
            for (int c = 0; c < 4; ++c)
#pragma unroll
                for (int e = 0; e < 8; ++e) xaf[c][e] = (_Float16)bf2f(xru[c][e]);
        } else {
#pragma unroll
            for (int c = 0; c < 4; ++c)
#pragma unroll
                for (int e = 0; e < 8; ++e) xaf[c][e] = (_Float16)xrf[2 * c + (e >> 2)][e & 3];
        }
    };
    // one N-tile of the xproj chunk (split across two slices to avoid an
    // 8-MFMA+8-store single-step burst that stalls the whole-block barrier)
    auto xmm1 = [&](float* dst, int tt) {
        f32x4 xa = kz;
#pragma unroll
        for (int c = 0; c < 4; ++c)
            xa = __builtin_amdgcn_mfma_f32_16x16x32_f16(xaf[c], bfrag[(8 + c) * 2 + tt], xa, 0, 0, 0);
        // D layout: col = lane&15 (-> j), row = (lane>>4)*4 + r (-> t')
#pragma unroll
        for (int r = 0; r < 4; ++r)
            dst[(quad * 4 + r) * XPLD + w * 32 + tt * 16 + col] = xa[r];
    };

    // ---- init h (fp32 state; publish hi/lo operand halves) ----
    float hreg;
    {
        if (!f32io) hreg = bf2f(((const unsigned short*)hxv)[b * HH + jown]);
        else        hreg = ((const float*)hxv)[b * HH + jown];
        _Float16 hi = (_Float16)hreg;
        _Float16 lo = (_Float16)((hreg - (float)hi) * 2048.f);
        s_h[0][jown]        = hi;   // duplicate lanes write identical values
        s_h[0][LOFF + jown] = lo;
    }

    // ---- prologue: xproj for chunk 0 ----
    xload(0); xcvt(); xmm1(&s_xp[0][0], 0); xmm1(&s_xp[0][0], 1);
    __syncthreads();

    for (int t = 0; t < TT; ++t) {
        const int par   = t & 1;
        const int slot  = (t >> 4) & 1;
        const int slice = t & 15;
        const int tn    = (t & ~15) + 16;       // next chunk base
        const bool prep = (tn < TT);

        // chunk n+1 prep pipeline: load @slice0, cvt @slice4, mfma+store @8,9
        if (slice == 0 && prep) xload(tn);

        const float xp = s_xp[slot][slice * XPLD + jown];

        const _Float16* hb = s_h[par];

        if (slice == 4 && prep) xcvt();
        if (slice == 8 && prep) xmm1(&s_xp[slot ^ 1][0], 0);
        if (slice == 9 && prep) xmm1(&s_xp[slot ^ 1][0], 1);

        // recurrence MFMAs: one read + one MFMA per K-chunk covers hi AND lo
        // (hi rides A-rows %4==0 -> acc reg0; lo rides rows %4==1 -> reg1)
        f32x4 acc0, acc1;
        {   // c = 0, seed with persistent zero
            f16x8 a = *(const f16x8*)(hb + aoff + quad * 8);
            acc0 = __builtin_amdgcn_mfma_f32_16x16x32_f16(a, bfrag[0], kz, 0, 0, 0);
            acc1 = __builtin_amdgcn_mfma_f32_16x16x32_f16(a, bfrag[1], kz, 0, 0, 0);
        }
#pragma unroll
        for (int c = 1; c < 8; ++c) {
            f16x8 a = *(const f16x8*)(hb + aoff + 32 * c + quad * 8);
            acc0 = __builtin_amdgcn_mfma_f32_16x16x32_f16(a, bfrag[c * 2 + 0], acc0, 0, 0, 0);
            acc1 = __builtin_amdgcn_mfma_f32_16x16x32_f16(a, bfrag[c * 2 + 1], acc1, 0, 0, 0);
        }

        // lane (any quad) holds D rows 4q (hi) and 4q+1 (lo) at its col
        float ph = tsel ? acc1[0] : acc0[0];
        float pl = tsel ? acc1[1] : acc0[1];
        float pre = (ph + xp) + pl * (1.f / 2048.f);   // same order as R3 (absmax-proven)

        hreg = 0.8f * hreg + 0.2f * fmaxf(pre, 0.f);

        _Float16 hi = (_Float16)hreg;
        _Float16 lo = (_Float16)((hreg - (float)hi) * 2048.f);
        s_h[par ^ 1][jown]        = hi;         // duplicate lanes: same value, same addr
        s_h[par ^ 1][LOFF + jown] = lo;

        if (t == TT - 1) s_hf[jown] = hreg;     // publish fp32 h for heads
        __syncthreads();
    }

    // ---- epilogue ----
    // new_hx: out[2304 + b*256 + j] (fp32 state)
    if (l < 32) {
        if (!f32io) ((__hip_bfloat16*)outv)[2304 + b * HH + jown] = __float2bfloat16(hreg);
        else        ((float*)outv)[2304 + b * HH + jown] = hreg;
    }

    // actor_logits out[b*8 + a], critic out[2048 + b]
    if (tid < 9) {
        float acc = 0.f;
        if (!f32io) {
            const unsigned short* wr = (tid < 8) ? ((const unsigned short*)Wactv + tid * HH)
                                                 : (const unsigned short*)Wcritv;
            for (int i = 0; i < HH; ++i) acc += bf2f(wr[i]) * s_hf[i];
        } else {
            const float* wr = (tid < 8) ? ((const float*)Wactv + tid * HH)
                                        : (const float*)Wcritv;
            for (int i = 0; i < HH; ++i) acc += wr[i] * s_hf[i];
        }
        const int idx = (tid < 8) ? (b * 8 + tid) : (2048 + b);
        if (!f32io) ((__hip_bfloat16*)outv)[idx] = __float2bfloat16(acc);
        else        ((float*)outv)[idx] = acc;
    }
}

extern "C" void kernel_launch(void* const* d_in, const int* in_sizes, int n_in,
                              void* d_out, int out_size, void* d_ws, size_t ws_size,
                              hipStream_t stream) {
    // dict order: x [256,2048,128], hx [1,256,256], W_ih [256,128],
    //             W_hh [256,256], W_actor [8,256], W_critic [1,256]
    rnn_mfma_r4<<<dim3(BB), dim3(512), 0, stream>>>(
        d_in[0], d_in[1], d_in[2], d_in[3], d_in[4], d_in[5], d_out);
}

// Round 5
// 1564.636 us; speedup vs baseline: 1.0643x; 1.0643x over previous
//
#include <hip/hip_runtime.h>
#include <hip/hip_bf16.h>
#include <stdint.h>

// ContinuousActorCritic: B=256, T=2048, I=128, H=256, A=8
#define BB 256
#define TT 2048
#define II 128
#define HH 256
#define XPLD 260   // s_xp row stride (floats); 256+4 pad keeps write conflicts at free 2-way
#define LOFF 288   // lo half offset in s_h (f16 elems). Byte dist 576 = 64 mod 128 ->
                   // hi/lo reads tile all 32 banks exactly once (R4-verified: conflicts 1.3e8 -> 0)

typedef _Float16       f16x8     __attribute__((ext_vector_type(8)));  // 4 VGPR
typedef float          f32x4     __attribute__((ext_vector_type(4)));
typedef unsigned short ushort8_t __attribute__((ext_vector_type(8)));
typedef float          float4_t  __attribute__((ext_vector_type(4)));

__device__ __forceinline__ float bf2f(unsigned short u) {
    union { unsigned int i; float f; } v; v.i = ((unsigned int)u) << 16; return v.f;
}

// R5 = R4 skeleton (hi/lo precision split in MFMA A-rows: rows%4==0 = h_hi,
// rows%4==1 = h_lo*2048; one ds_read + one MFMA per K-chunk covers both;
// acc reg0 = hi, reg1 = lo) with three serial-path cuts (R4 post-mortem: the
// ~1250 cy/step residual is latency, not LDS bandwidth — halving LDS traffic
// and zeroing conflicts didn't move it):
//  1. chain-split: K=256 as two depth-4 partial chains per tile + fp32 add
//     (4 independent chains/wave, halves dependent-MFMA latency term)
//  2. raw barrier: s_waitcnt lgkmcnt(0) + s_barrier (no vmcnt(0) drain!) —
//     __syncthreads was draining the slice-0 HBM prefetch (~900 cy / 16 steps)
//  3. single ds_write: lanes<32 write hi@jown, lanes>=32 write lo@LOFF+jown
//     (was 2 writes with 2-way same-address lane duplication)
// 512 threads = 8 waves = 2/SIMD; wave w owns outputs [w*32, w*32+32) as 2
// N-tiles. xproj batched per 16-step chunk via MFMA M-dim = timesteps
// (load@0, cvt@4, mfma+store@8 — single-slice dual-tile, R3's faster form).
__global__ __launch_bounds__(512, 2)
void rnn_mfma_r5(const void* __restrict__ xv,  const void* __restrict__ hxv,
                 const void* __restrict__ Wihv, const void* __restrict__ Whhv,
                 const void* __restrict__ Wactv, const void* __restrict__ Wcritv,
                 void* __restrict__ outv)
{
    const int b    = blockIdx.x;
    const int tid  = threadIdx.x;
    const int w    = tid >> 6;            // 0..7
    const int l    = tid & 63;
    const int quad = l >> 4;
    const int col  = l & 15;
    const int tsel = (l >> 4) & 1;        // which N-tile this lane extracts
    const int jown = w * 32 + (l & 31);   // owned output (lanes 32-63 duplicate)
    const int aoff = ((l & 3) == 1) ? LOFF : 0;      // A-row%4==1 lanes feed lo
    const int woff = ((l < 32) ? 0 : LOFF) + jown;   // single-write address

    __shared__ __align__(16) _Float16 s_h[2][2 * LOFF];  // [k]=h_hi, [LOFF+k]=h_lo*2048; dbuf
    __shared__ __align__(16) float    s_xp[2][16 * XPLD];// xproj chunk, dbuf
    __shared__ float s_hf[HH];                           // final h fp32 (heads)
    __shared__ int s_flag;

    // ---- storage-dtype detector (bf16 expected) ----
    if (tid == 0) {
        const unsigned short* p = (const unsigned short*)Whhv;
        int cnt = 0;
        for (int i = 0; i < 256; ++i) { int e = (p[i] >> 7) & 0xFF; cnt += (e > 128) ? 1 : 0; }
        s_flag = (cnt > 16) ? 1 : 0;   // 1 => fp32 storage
    }
    __syncthreads();
    const bool f32io = (s_flag != 0);

    // ---- B-fragments, register-stationary, f16 (bf16->f16 exact) ----
    // bfrag[c*2+t]: lane holds W(j, k0..k0+7), j = w*32 + t*16 + col,
    // k0 = 32c + quad*8.  c 0..7: W_hh; c 8..11: W_ih (xproj chunks).
    f16x8 bfrag[24];
#pragma unroll
    for (int c = 0; c < 12; ++c) {
#pragma unroll
        for (int t = 0; t < 2; ++t) {
            const int j  = w * 32 + t * 16 + col;
            const int k0 = 32 * c + quad * 8;
            f16x8 bv;
            if (!f32io) {
                const unsigned short* src = (k0 < HH)
                    ? ((const unsigned short*)Whhv + j * HH + k0)
                    : ((const unsigned short*)Wihv + j * II + (k0 - HH));
                ushort8_t u = *(const ushort8_t*)src;
#pragma unroll
                for (int e = 0; e < 8; ++e) bv[e] = (_Float16)bf2f(u[e]);
            } else {
                const float* src = (k0 < HH)
                    ? ((const float*)Whhv + j * HH + k0)
                    : ((const float*)Wihv + j * II + (k0 - HH));
#pragma unroll
                for (int e = 0; e < 8; ++e) bv[e] = (_Float16)src[e];
            }
            bfrag[c * 2 + t] = bv;
        }
    }

    const f32x4 kz = {0.f, 0.f, 0.f, 0.f};

    // ---- xproj chunk-prep machinery ----
    // A-frag layout: row m = lane&15 (= timestep-in-chunk), k = (lane>>4)*8+e.
    ushort8_t xru[4];   // raw bf16 prefetch
    float4_t  xrf[8];   // raw fp32 prefetch
    f16x8     xaf[4];   // converted A-frags

    auto xload = [&](int tbase) {
        if (!f32io) {
            const unsigned short* gp = (const unsigned short*)xv
                + ((size_t)b * TT + tbase + col) * II + quad * 8;
#pragma unroll
            for (int c = 0; c < 4; ++c) xru[c] = *(const ushort8_t*)(gp + 32 * c);
        } else {
            const float* gp = (const float*)xv
                + ((size_t)b * TT + tbase + col) * II + quad * 8;
#pragma unroll
            for (int c = 0; c < 4; ++c) {
                xrf[2 * c]     = *(const float4_t*)(gp + 32 * c);
                xrf[2 * c + 1] = *(const float4_t*)(gp + 32 * c + 4);
            }
        }
    };
    auto xcvt = [&]() {
        if (!f32io) {
#pragma unroll
            for (int c = 0; c < 4; ++c)
#pragma unroll
                for (int e = 0; e < 8; ++e) xaf[c][e] = (_Float16)bf2f(xru[c][e]);
        } else {
#pragma unroll
            for (int c = 0; c < 4; ++c)
#pragma unroll
                for (int e = 0; e < 8; ++e) xaf[c][e] = (_Float16)xrf[2 * c + (e >> 2)][e & 3];
        }
    };
    auto xmm = [&](float* dst) {
        f32x4 xa[2];
        xa[0] = kz; xa[1] = kz;
#pragma unroll
        for (int c = 0; c < 4; ++c)
#pragma unroll
            for (int tt = 0; tt < 2; ++tt)
                xa[tt] = __builtin_amdgcn_mfma_f32_16x16x32_f16(xaf[c], bfrag[(8 + c) * 2 + tt], xa[tt], 0, 0, 0);
        // D layout: col = lane&15 (-> j), row = (lane>>4)*4 + r (-> t')
#pragma unroll
        for (int tt = 0; tt < 2; ++tt)
#pragma unroll
            for (int r = 0; r < 4; ++r)
                dst[(quad * 4 + r) * XPLD + w * 32 + tt * 16 + col] = xa[tt][r];
    };

    // ---- init h (fp32 state; publish hi/lo operand halves) ----
    float hreg;
    {
        if (!f32io) hreg = bf2f(((const unsigned short*)hxv)[b * HH + jown]);
        else        hreg = ((const float*)hxv)[b * HH + jown];
        _Float16 hi = (_Float16)hreg;
        _Float16 lo = (_Float16)((hreg - (float)hi) * 2048.f);
        s_h[0][jown]        = hi;   // duplicate lanes write identical values
        s_h[0][LOFF + jown] = lo;
    }

    // ---- prologue: xproj for chunk 0 ----
    xload(0); xcvt(); xmm(&s_xp[0][0]);
    __syncthreads();

    for (int t = 0; t < TT; ++t) {
        const int par   = t & 1;
        const int slot  = (t >> 4) & 1;
        const int slice = t & 15;
        const int tn    = (t & ~15) + 16;       // next chunk base
        const bool prep = (tn < TT);

        // chunk n+1 prep pipeline: load @slice0 (stays in flight across raw
        // barriers — no vmcnt drain now), cvt @slice4, mfma+store @slice8
        if (slice == 0 && prep) xload(tn);

        const float xp = s_xp[slot][slice * XPLD + jown];

        const _Float16* hb = s_h[par];

        if (slice == 4 && prep) xcvt();
        if (slice == 8 && prep) xmm(&s_xp[slot ^ 1][0]);

        // recurrence MFMAs: one read + one MFMA per K-chunk covers hi AND lo.
        // K split in two depth-4 chains per tile (4 independent chains/wave).
        f32x4 acc0a, acc1a, acc0b, acc1b;
        {   // a-chains seed at c=0
            f16x8 a = *(const f16x8*)(hb + aoff + quad * 8);
            acc0a = __builtin_amdgcn_mfma_f32_16x16x32_f16(a, bfrag[0], kz, 0, 0, 0);
            acc1a = __builtin_amdgcn_mfma_f32_16x16x32_f16(a, bfrag[1], kz, 0, 0, 0);
        }
        {   // b-chains seed at c=4
            f16x8 a = *(const f16x8*)(hb + aoff + 32 * 4 + quad * 8);
            acc0b = __builtin_amdgcn_mfma_f32_16x16x32_f16(a, bfrag[8], kz, 0, 0, 0);
            acc1b = __builtin_amdgcn_mfma_f32_16x16x32_f16(a, bfrag[9], kz, 0, 0, 0);
        }
#pragma unroll
        for (int c = 1; c < 4; ++c) {
            f16x8 a = *(const f16x8*)(hb + aoff + 32 * c + quad * 8);
            acc0a = __builtin_amdgcn_mfma_f32_16x16x32_f16(a, bfrag[c * 2 + 0], acc0a, 0, 0, 0);
            acc1a = __builtin_amdgcn_mfma_f32_16x16x32_f16(a, bfrag[c * 2 + 1], acc1a, 0, 0, 0);
            f16x8 a2 = *(const f16x8*)(hb + aoff + 32 * (c + 4) + quad * 8);
            acc0b = __builtin_amdgcn_mfma_f32_16x16x32_f16(a2, bfrag[(c + 4) * 2 + 0], acc0b, 0, 0, 0);
            acc1b = __builtin_amdgcn_mfma_f32_16x16x32_f16(a2, bfrag[(c + 4) * 2 + 1], acc1b, 0, 0, 0);
        }

        // lane holds D rows 4q (hi, reg0) and 4q+1 (lo, reg1) at its col
        float pha = tsel ? acc1a[0] : acc0a[0];
        float phb = tsel ? acc1b[0] : acc0b[0];
        float pla = tsel ? acc1a[1] : acc0a[1];
        float plb = tsel ? acc1b[1] : acc0b[1];
        float ph = pha + phb;
        float pl = pla + plb;
        float pre = (ph + xp) + pl * (1.f / 2048.f);

        hreg = 0.8f * hreg + 0.2f * fmaxf(pre, 0.f);

        _Float16 hi = (_Float16)hreg;
        _Float16 lo = (_Float16)((hreg - (float)hi) * 2048.f);
        s_h[par ^ 1][woff] = (l < 32) ? hi : lo;   // one write, no addr collisions

        if (t == TT - 1) s_hf[jown] = hreg;        // publish fp32 h for heads

        // raw barrier: drain LDS writes only (NOT vmcnt — keep HBM prefetch
        // in flight). m201-proven pattern; sched_barrier pins ordering.
        asm volatile("s_waitcnt lgkmcnt(0)" ::: "memory");
        __builtin_amdgcn_s_barrier();
        __builtin_amdgcn_sched_barrier(0);
    }

    // ---- epilogue ----
    // new_hx: out[2304 + b*256 + j] (fp32 state)
    if (l < 32) {
        if (!f32io) ((__hip_bfloat16*)outv)[2304 + b * HH + jown] = __float2bfloat16(hreg);
        else        ((float*)outv)[2304 + b * HH + jown] = hreg;
    }

    // actor_logits out[b*8 + a], critic out[2048 + b]
    if (tid < 9) {
        float acc = 0.f;
        if (!f32io) {
            const unsigned short* wr = (tid < 8) ? ((const unsigned short*)Wactv + tid * HH)
                                                 : (const unsigned short*)Wcritv;
            for (int i = 0; i < HH; ++i) acc += bf2f(wr[i]) * s_hf[i];
        } else {
            const float* wr = (tid < 8) ? ((const float*)Wactv + tid * HH)
                                        : (const float*)Wcritv;
            for (int i = 0; i < HH; ++i) acc += wr[i] * s_hf[i];
        }
        const int idx = (tid < 8) ? (b * 8 + tid) : (2048 + b);
        if (!f32io) ((__hip_bfloat16*)outv)[idx] = __float2bfloat16(acc);
        else        ((float*)outv)[idx] = acc;
    }
}

extern "C" void kernel_launch(void* const* d_in, const int* in_sizes, int n_in,
                              void* d_out, int out_size, void* d_ws, size_t ws_size,
                              hipStream_t stream) {
    // dict order: x [256,2048,128], hx [1,256,256], W_ih [256,128],
    //             W_hh [256,256], W_actor [8,256], W_critic [1,256]
    rnn_mfma_r5<<<dim3(BB), dim3(512), 0, stream>>>(
        d_in[0], d_in[1], d_in[2], d_in[3], d_in[4], d_in[5], d_out);
}